// Round 3
// baseline (1145.162 us; speedup 1.0000x reference)
//
#include <hip/hip_runtime.h>
#include <math.h>

#define EPSV 1e-5f

// conv1 (3-tap, zero-pad) + relu at the 3 positions of one sample
__device__ __forceinline__ void conv3_relu(float x0, float x1, float x2,
                                           float wa, float wb, float wc, float bb,
                                           float& t0, float& t1, float& t2)
{
    t0 = fmaxf(fmaf(wb, x0, fmaf(wc, x1, bb)), 0.f);
    t1 = fmaxf(fmaf(wa, x0, fmaf(wb, x1, fmaf(wc, x2, bb))), 0.f);
    t2 = fmaxf(fmaf(wa, x1, fmaf(wb, x2, bb)), 0.f);
}

// ---------------------------------------------------------------------------
// Pass 1: per-channel sum/sumsq of relu(conv1(x)+b1), 16 channels.
// One lane = 4 consecutive samples (3 float4 loads). Weights in LDS
// (uniform-address broadcast reads). Tail: xor-tree, lane L ends with slot L.
// partials[block*32 + v]: v<16 sum[ch v], v>=16 sq[ch v-16]
// ---------------------------------------------------------------------------
__global__ __launch_bounds__(256, 4) void k_stats1(const float* __restrict__ x,
                                                   const float* __restrict__ w1,
                                                   const float* __restrict__ b1,
                                                   float* __restrict__ partials,
                                                   int B)
{
    __shared__ float4 sW1[16];
    int t = threadIdx.x;
    if (t < 16) sW1[t] = make_float4(w1[3*t], w1[3*t+1], w1[3*t+2], b1[t]);
    __syncthreads();

    float cur[32];   // [0,16): sum, [16,32): sq
#pragma unroll
    for (int i = 0; i < 32; ++i) cur[i] = 0.f;

    int nchunk = (B + 3) >> 2;
    for (int ch = blockIdx.x * 256 + t; ch < nchunk; ch += gridDim.x * 256) {
        int s0 = ch << 2;
        float X[4][3];
        if (s0 + 4 <= B) {
            const float4* xp = (const float4*)(x + (size_t)s0 * 3);
            float4 A = xp[0], Bq = xp[1], Cq = xp[2];
            X[0][0]=A.x;  X[0][1]=A.y;  X[0][2]=A.z;
            X[1][0]=A.w;  X[1][1]=Bq.x; X[1][2]=Bq.y;
            X[2][0]=Bq.z; X[2][1]=Bq.w; X[2][2]=Cq.x;
            X[3][0]=Cq.y; X[3][1]=Cq.z; X[3][2]=Cq.w;
        } else {
#pragma unroll
            for (int m = 0; m < 4; ++m) {
                int s = s0 + m;
                if (s < B) { X[m][0]=x[3*s]; X[m][1]=x[3*s+1]; X[m][2]=x[3*s+2]; }
                else { X[m][0]=X[m][1]=X[m][2]=0.f; }
            }
        }
#pragma unroll
        for (int g = 0; g < 16; ++g) {
            float4 w = sW1[g];
#pragma unroll
            for (int m = 0; m < 4; ++m) {
                if (s0 + m < B) {
                    float t0, t1, t2;
                    conv3_relu(X[m][0], X[m][1], X[m][2], w.x, w.y, w.z, w.w, t0, t1, t2);
                    cur[g]      += t0 + t1 + t2;
                    cur[16 + g]  = fmaf(t0, t0, fmaf(t1, t1, fmaf(t2, t2, cur[16 + g])));
                }
            }
        }
    }

    // xor-tree: 32 slots across 64 lanes -> lane (L&31) holds total of slot (L&31)
    int lane = t & 63, wid = t >> 6;
#pragma unroll
    for (int i = 0; i < 32; ++i) cur[i] += __shfl_xor(cur[i], 32, 64);
#pragma unroll
    for (int half = 16; half >= 1; half >>= 1) {
#pragma unroll
        for (int i = 0; i < half; ++i) {
            bool up = (lane & half);
            float keep = up ? cur[i + half] : cur[i];
            float send = up ? cur[i] : cur[i + half];
            cur[i] = keep + __shfl_xor(send, half, 64);
        }
    }
    __shared__ float red[4][32];
    if (lane < 32) red[wid][lane] = cur[0];
    __syncthreads();
    if (t < 32)
        partials[blockIdx.x * 32 + t] = red[0][t] + red[1][t] + red[2][t] + red[3][t];
}

// ---------------------------------------------------------------------------
// Finalize 1: BN1 scale/shift, fold into conv2 weights (padding-aware bias).
// ---------------------------------------------------------------------------
__global__ __launch_bounds__(256) void k_fin1(const float* __restrict__ partials,
                                              const float* __restrict__ g1,
                                              const float* __restrict__ bt1,
                                              const float* __restrict__ w2,
                                              const float* __restrict__ b2,
                                              float* __restrict__ w2f,
                                              float* __restrict__ b2f,
                                              float Ninv, int nb)
{
    __shared__ float4 red4[32][8];
    __shared__ float tot[32];
    __shared__ float ssc[16], ssh[16];
    int t = threadIdx.x;
    {
        int v4 = t & 7, c = t >> 3;  // 8 float4 slots cover 32 floats; 32 chunks
        float4 a = make_float4(0.f, 0.f, 0.f, 0.f);
        for (int b = c; b < nb; b += 32) {
            float4 p = ((const float4*)partials)[b * 8 + v4];
            a.x += p.x; a.y += p.y; a.z += p.z; a.w += p.w;
        }
        red4[c][v4] = a;
    }
    __syncthreads();
    if (t < 8) {
        float4 a = make_float4(0.f, 0.f, 0.f, 0.f);
#pragma unroll
        for (int c = 0; c < 32; ++c) {
            float4 p = red4[c][t];
            a.x += p.x; a.y += p.y; a.z += p.z; a.w += p.w;
        }
        tot[4*t+0] = a.x; tot[4*t+1] = a.y; tot[4*t+2] = a.z; tot[4*t+3] = a.w;
    }
    __syncthreads();
    if (t < 16) {
        float mean = tot[t] * Ninv;
        float var  = fmaxf(tot[16 + t] * Ninv - mean * mean, 0.f);
        float rstd = rsqrtf(var + EPSV);
        float sc = g1[t] * rstd;
        ssc[t] = sc;
        ssh[t] = bt1[t] - mean * sc;
    }
    __syncthreads();
    if (t < 96) {
        int o = t / 3, p = t % 3;
        int g = o >> 1;
        w2f[t] = w2[t] * ssc[g];
        float wv0 = w2[3*o], wv1 = w2[3*o+1], wv2 = w2[3*o+2];
        float sv = (p == 0) ? (wv1 + wv2) : ((p == 1) ? (wv0 + wv1 + wv2) : (wv0 + wv1));
        b2f[t] = b2[o] + ssh[g] * sv;
    }
}

// ---------------------------------------------------------------------------
// Pass 2: per-channel sum/sumsq of relu(conv2(bn1(relu1))), 32 channels.
// One lane = 4 consecutive samples; all weights LDS-broadcast; no per-sample
// cross-lane ops. Tail: xor-tree over 64 slots.
// partials[block*64 + v]: v<32 sum[ch v], v>=32 sq[ch v-32]
// ---------------------------------------------------------------------------
__global__ __launch_bounds__(256, 4) void k_stats2(const float* __restrict__ x,
                                                   const float* __restrict__ w1,
                                                   const float* __restrict__ b1,
                                                   const float* __restrict__ w2f,
                                                   const float* __restrict__ b2f,
                                                   float* __restrict__ partials,
                                                   int B)
{
    __shared__ float4 sW1[16];
    __shared__ float4 sU[32];   // ua,ub,uc,c0
    __shared__ float2 sC[32];   // c1,c2
    int t = threadIdx.x;
    if (t < 16) sW1[t] = make_float4(w1[3*t], w1[3*t+1], w1[3*t+2], b1[t]);
    else if (t >= 32 && t < 64) {
        int o = t - 32;
        sU[o] = make_float4(w2f[3*o], w2f[3*o+1], w2f[3*o+2], b2f[3*o]);
        sC[o] = make_float2(b2f[3*o+1], b2f[3*o+2]);
    }
    __syncthreads();

    float cur[64];  // [0,32): sum, [32,64): sq
#pragma unroll
    for (int i = 0; i < 64; ++i) cur[i] = 0.f;

    int nchunk = (B + 3) >> 2;
    for (int ch = blockIdx.x * 256 + t; ch < nchunk; ch += gridDim.x * 256) {
        int s0 = ch << 2;
        float X[4][3];
        if (s0 + 4 <= B) {
            const float4* xp = (const float4*)(x + (size_t)s0 * 3);
            float4 A = xp[0], Bq = xp[1], Cq = xp[2];
            X[0][0]=A.x;  X[0][1]=A.y;  X[0][2]=A.z;
            X[1][0]=A.w;  X[1][1]=Bq.x; X[1][2]=Bq.y;
            X[2][0]=Bq.z; X[2][1]=Bq.w; X[2][2]=Cq.x;
            X[3][0]=Cq.y; X[3][1]=Cq.z; X[3][2]=Cq.w;
        } else {
#pragma unroll
            for (int m = 0; m < 4; ++m) {
                int s = s0 + m;
                if (s < B) { X[m][0]=x[3*s]; X[m][1]=x[3*s+1]; X[m][2]=x[3*s+2]; }
                else { X[m][0]=X[m][1]=X[m][2]=0.f; }
            }
        }
#pragma unroll
        for (int g = 0; g < 16; ++g) {
            float4 w = sW1[g];
            float r[4][3];
#pragma unroll
            for (int m = 0; m < 4; ++m)
                conv3_relu(X[m][0], X[m][1], X[m][2], w.x, w.y, w.z, w.w,
                           r[m][0], r[m][1], r[m][2]);
#pragma unroll
            for (int jj = 0; jj < 2; ++jj) {
                int o = 2 * g + jj;
                float4 u = sU[o];
                float2 cc = sC[o];
#pragma unroll
                for (int m = 0; m < 4; ++m) {
                    if (s0 + m < B) {
                        float v0 = fmaxf(fmaf(u.y, r[m][0], fmaf(u.z, r[m][1], u.w)), 0.f);
                        float v1 = fmaxf(fmaf(u.x, r[m][0], fmaf(u.y, r[m][1], fmaf(u.z, r[m][2], cc.x))), 0.f);
                        float v2 = fmaxf(fmaf(u.x, r[m][1], fmaf(u.y, r[m][2], cc.y)), 0.f);
                        cur[o]      += v0 + v1 + v2;
                        cur[32 + o]  = fmaf(v0, v0, fmaf(v1, v1, fmaf(v2, v2, cur[32 + o])));
                    }
                }
            }
        }
    }

    // xor-tree: 64 slots across 64 lanes -> lane L holds total of slot L
    int lane = t & 63, wid = t >> 6;
#pragma unroll
    for (int half = 32; half >= 1; half >>= 1) {
#pragma unroll
        for (int i = 0; i < half; ++i) {
            bool up = (lane & half);
            float keep = up ? cur[i + half] : cur[i];
            float send = up ? cur[i] : cur[i + half];
            cur[i] = keep + __shfl_xor(send, half, 64);
        }
    }
    __shared__ float red[4][64];
    red[wid][lane] = cur[0];
    __syncthreads();
    if (t < 64)
        partials[blockIdx.x * 64 + t] = red[0][t] + red[1][t] + red[2][t] + red[3][t];
}

// ---------------------------------------------------------------------------
// Finalize 2: BN2 scale/shift, fold BN2 + mean(1/3) into fc1.
// ---------------------------------------------------------------------------
__global__ __launch_bounds__(256) void k_fin2(const float* __restrict__ partials,
                                              const float* __restrict__ g2,
                                              const float* __restrict__ bt2,
                                              const float* __restrict__ fw1,
                                              const float* __restrict__ fb1,
                                              float* __restrict__ fw1s,
                                              float* __restrict__ c1,
                                              float Ninv, int nb)
{
    __shared__ float4 red4[16][16];
    __shared__ float tot[64];
    __shared__ float ssc[32], ssh[32];
    int t = threadIdx.x;
    {
        int v4 = t & 15, c = t >> 4;  // 16 float4 slots cover 64 floats; 16 chunks
        float4 a = make_float4(0.f, 0.f, 0.f, 0.f);
        for (int b = c; b < nb; b += 16) {
            float4 p = ((const float4*)partials)[b * 16 + v4];
            a.x += p.x; a.y += p.y; a.z += p.z; a.w += p.w;
        }
        red4[c][v4] = a;
    }
    __syncthreads();
    if (t < 16) {
        float4 a = make_float4(0.f, 0.f, 0.f, 0.f);
#pragma unroll
        for (int c = 0; c < 16; ++c) {
            float4 p = red4[c][t];
            a.x += p.x; a.y += p.y; a.z += p.z; a.w += p.w;
        }
        tot[4*t+0] = a.x; tot[4*t+1] = a.y; tot[4*t+2] = a.z; tot[4*t+3] = a.w;
    }
    __syncthreads();
    if (t < 32) {
        float mean = tot[t] * Ninv;
        float var  = fmaxf(tot[32 + t] * Ninv - mean * mean, 0.f);
        float rstd = rsqrtf(var + EPSV);
        float sc = g2[t] * rstd;
        ssc[t] = sc;
        ssh[t] = bt2[t] - mean * sc;
    }
    __syncthreads();
    for (int idx = t; idx < 512; idx += 256) {
        int c = idx & 31;
        fw1s[idx] = fw1[idx] * ssc[c] * (1.0f / 3.0f);
    }
    if (t < 16) {
        float a = fb1[t];
#pragma unroll
        for (int c = 0; c < 32; ++c) a = fmaf(fw1[t * 32 + c], ssh[c], a);
        c1[t] = a;
    }
}

// ---------------------------------------------------------------------------
// Pass 3: full forward, one lane = 2 consecutive samples, no cross-lane ops.
// All weights LDS-broadcast. fc1 j-outer with 2x2 partial accumulators.
// ---------------------------------------------------------------------------
__global__ __launch_bounds__(256, 4) void k_final(const float* __restrict__ x,
                                                  const float* __restrict__ w1,
                                                  const float* __restrict__ b1,
                                                  const float* __restrict__ w2f,
                                                  const float* __restrict__ b2f,
                                                  const float* __restrict__ fw1s,
                                                  const float* __restrict__ c1,
                                                  const float* __restrict__ fw2,
                                                  const float* __restrict__ fb2,
                                                  float* __restrict__ out,
                                                  int B)
{
    __shared__ float4 sW1[16];
    __shared__ float4 sU[32];
    __shared__ float2 sC[32];
    __shared__ float4 sF[128];   // fw1s rows: sF[j*8+k] = fw1s[j*32+4k .. +3]
    __shared__ float2 sJ[16];    // (c1[j], fw2[j])
    __shared__ float  sb2;
    int t = threadIdx.x;
    if (t < 16) sW1[t] = make_float4(w1[3*t], w1[3*t+1], w1[3*t+2], b1[t]);
    else if (t >= 32 && t < 64) {
        int o = t - 32;
        sU[o] = make_float4(w2f[3*o], w2f[3*o+1], w2f[3*o+2], b2f[3*o]);
        sC[o] = make_float2(b2f[3*o+1], b2f[3*o+2]);
    } else if (t >= 64 && t < 192) {
        sF[t - 64] = ((const float4*)fw1s)[t - 64];
    } else if (t >= 192 && t < 208) {
        sJ[t - 192] = make_float2(c1[t - 192], fw2[t - 192]);
    } else if (t == 224) {
        sb2 = fb2[0];
    }
    __syncthreads();

    int nchunk = (B + 1) >> 1;
    for (int ch = blockIdx.x * 256 + t; ch < nchunk; ch += gridDim.x * 256) {
        int s0 = ch << 1;
        bool pair = (s0 + 2 <= B);
        float xA0, xA1, xA2, xB0, xB1, xB2;
        if (pair) {
            const float2* xp = (const float2*)(x + (size_t)s0 * 3);
            float2 a = xp[0], b = xp[1], c = xp[2];
            xA0 = a.x; xA1 = a.y; xA2 = b.x;
            xB0 = b.y; xB1 = c.x; xB2 = c.y;
        } else {
            xA0 = x[3*s0]; xA1 = x[3*s0+1]; xA2 = x[3*s0+2];
            xB0 = xB1 = xB2 = 0.f;
        }

        float sA[32], sB[32];
#pragma unroll
        for (int g = 0; g < 16; ++g) {
            float4 w = sW1[g];
            float rA0, rA1, rA2, rB0, rB1, rB2;
            conv3_relu(xA0, xA1, xA2, w.x, w.y, w.z, w.w, rA0, rA1, rA2);
            conv3_relu(xB0, xB1, xB2, w.x, w.y, w.z, w.w, rB0, rB1, rB2);
#pragma unroll
            for (int jj = 0; jj < 2; ++jj) {
                int o = 2 * g + jj;
                float4 u = sU[o];
                float2 cc = sC[o];
                float a0 = fmaxf(fmaf(u.y, rA0, fmaf(u.z, rA1, u.w)), 0.f);
                float a1 = fmaxf(fmaf(u.x, rA0, fmaf(u.y, rA1, fmaf(u.z, rA2, cc.x))), 0.f);
                float a2 = fmaxf(fmaf(u.x, rA1, fmaf(u.y, rA2, cc.y)), 0.f);
                sA[o] = a0 + a1 + a2;
                float b0 = fmaxf(fmaf(u.y, rB0, fmaf(u.z, rB1, u.w)), 0.f);
                float b1v = fmaxf(fmaf(u.x, rB0, fmaf(u.y, rB1, fmaf(u.z, rB2, cc.x))), 0.f);
                float b2v = fmaxf(fmaf(u.x, rB1, fmaf(u.y, rB2, cc.y)), 0.f);
                sB[o] = b0 + b1v + b2v;
            }
        }

        float base = sb2;
        float outA = base, outB = base;
#pragma unroll
        for (int j = 0; j < 16; ++j) {
            float a0 = 0.f, a1 = 0.f, b0 = 0.f, b1v = 0.f;
#pragma unroll
            for (int k = 0; k < 8; ++k) {
                float4 f = sF[j * 8 + k];
                a0  = fmaf(f.x, sA[4*k+0], a0);
                a1  = fmaf(f.y, sA[4*k+1], a1);
                a0  = fmaf(f.z, sA[4*k+2], a0);
                a1  = fmaf(f.w, sA[4*k+3], a1);
                b0  = fmaf(f.x, sB[4*k+0], b0);
                b1v = fmaf(f.y, sB[4*k+1], b1v);
                b0  = fmaf(f.z, sB[4*k+2], b0);
                b1v = fmaf(f.w, sB[4*k+3], b1v);
            }
            float2 jw = sJ[j];
            float hA = fmaxf(a0 + a1 + jw.x, 0.f);
            float hB = fmaxf(b0 + b1v + jw.x, 0.f);
            outA = fmaf(jw.y, hA, outA);
            outB = fmaf(jw.y, hB, outB);
        }
        if (pair) {
            ((float2*)(out + s0))[0] = make_float2(outA, outB);
        } else {
            out[s0] = outA;
        }
    }
}

// ---------------------------------------------------------------------------
extern "C" void kernel_launch(void* const* d_in, const int* in_sizes, int n_in,
                              void* d_out, int out_size, void* d_ws, size_t ws_size,
                              hipStream_t stream)
{
    const float* x   = (const float*)d_in[0];
    const float* w1  = (const float*)d_in[1];
    const float* b1  = (const float*)d_in[2];
    const float* g1  = (const float*)d_in[3];
    const float* bt1 = (const float*)d_in[4];
    const float* w2  = (const float*)d_in[5];
    const float* b2  = (const float*)d_in[6];
    const float* g2  = (const float*)d_in[7];
    const float* bt2 = (const float*)d_in[8];
    const float* fw1 = (const float*)d_in[9];
    const float* fb1 = (const float*)d_in[10];
    const float* fw2 = (const float*)d_in[11];
    const float* fb2 = (const float*)d_in[12];

    int B = in_sizes[0] / 3;

    // stats grids: one lane per 4-sample chunk; exact fit for B=2^20
    int nb1 = 1024, nb2 = 1024;
    while ((size_t)(nb1 * 32 + nb2 * 64 + 720) * sizeof(float) > ws_size && nb1 > 1) {
        nb1 >>= 1; nb2 >>= 1;
    }
    {   // don't launch more stats blocks than there are chunks
        int need = ((B + 3) / 4 + 255) / 256;
        if (nb1 > need && need > 0) nb1 = need;
        if (nb2 > need && need > 0) nb2 = need;
    }

    float* ws   = (float*)d_ws;
    float* p1   = ws;                               // nb1*32
    float* p2   = ws + (size_t)nb1 * 32;            // nb2*64
    float* w2f  = p2 + (size_t)nb2 * 64;            // 96
    float* b2f  = w2f + 96;                         // 96
    float* fw1s = b2f + 96;                         // 512
    float* c1   = fw1s + 512;                       // 16

    float Ninv = 1.0f / (3.0f * (float)B);

    int gridF = ((B + 1) / 2 + 255) / 256;          // 2048 for B=2^20

    k_stats1<<<nb1, 256, 0, stream>>>(x, w1, b1, p1, B);
    k_fin1<<<1, 256, 0, stream>>>(p1, g1, bt1, w2, b2, w2f, b2f, Ninv, nb1);
    k_stats2<<<nb2, 256, 0, stream>>>(x, w1, b1, w2f, b2f, p2, B);
    k_fin2<<<1, 256, 0, stream>>>(p2, g2, bt2, fw1, fb1, fw1s, c1, Ninv, nb2);
    k_final<<<gridF, 256, 0, stream>>>(x, w1, b1, w2f, b2f, fw1s, c1,
                                       fw2, fb2, (float*)d_out, B);
}

// Round 4
// 626.295 us; speedup vs baseline: 1.8285x; 1.8285x over previous
//
#include <hip/hip_runtime.h>
#include <math.h>

#define EPSV 1e-5f

// conv1 (3-tap, zero-pad) + relu at the 3 positions of one sample
__device__ __forceinline__ void conv3_relu(float x0, float x1, float x2,
                                           float wa, float wb, float wc, float bb,
                                           float& t0, float& t1, float& t2)
{
    t0 = fmaxf(fmaf(wb, x0, fmaf(wc, x1, bb)), 0.f);
    t1 = fmaxf(fmaf(wa, x0, fmaf(wb, x1, fmaf(wc, x2, bb))), 0.f);
    t2 = fmaxf(fmaf(wa, x1, fmaf(wb, x2, bb)), 0.f);
}

// ---------------------------------------------------------------------------
// Pass 1: per-channel sum/sumsq of relu(conv1(x)+b1), 16 channels.
// One lane = 4 consecutive samples (3 float4 loads). Weights in LDS
// (uniform-address broadcast reads). Tail: xor-tree, lane L ends with slot L.
// NOTE: plain __launch_bounds__(256) — adding ",4" capped VGPRs at 64 and
// spilled all per-lane state to scratch (R3: 2.65 GB traffic, 14x slowdown).
// partials[block*32 + v]: v<16 sum[ch v], v>=16 sq[ch v-16]
// ---------------------------------------------------------------------------
__global__ __launch_bounds__(256) void k_stats1(const float* __restrict__ x,
                                                const float* __restrict__ w1,
                                                const float* __restrict__ b1,
                                                float* __restrict__ partials,
                                                int B)
{
    __shared__ float4 sW1[16];
    int t = threadIdx.x;
    if (t < 16) sW1[t] = make_float4(w1[3*t], w1[3*t+1], w1[3*t+2], b1[t]);
    __syncthreads();

    float cur[32];   // [0,16): sum, [16,32): sq
#pragma unroll
    for (int i = 0; i < 32; ++i) cur[i] = 0.f;

    int nchunk = (B + 3) >> 2;
    for (int ch = blockIdx.x * 256 + t; ch < nchunk; ch += gridDim.x * 256) {
        int s0 = ch << 2;
        float X[4][3];
        if (s0 + 4 <= B) {
            const float4* xp = (const float4*)(x + (size_t)s0 * 3);
            float4 A = xp[0], Bq = xp[1], Cq = xp[2];
            X[0][0]=A.x;  X[0][1]=A.y;  X[0][2]=A.z;
            X[1][0]=A.w;  X[1][1]=Bq.x; X[1][2]=Bq.y;
            X[2][0]=Bq.z; X[2][1]=Bq.w; X[2][2]=Cq.x;
            X[3][0]=Cq.y; X[3][1]=Cq.z; X[3][2]=Cq.w;
        } else {
#pragma unroll
            for (int m = 0; m < 4; ++m) {
                int s = s0 + m;
                if (s < B) { X[m][0]=x[3*s]; X[m][1]=x[3*s+1]; X[m][2]=x[3*s+2]; }
                else { X[m][0]=X[m][1]=X[m][2]=0.f; }
            }
        }
#pragma unroll
        for (int g = 0; g < 16; ++g) {
            float4 w = sW1[g];
#pragma unroll
            for (int m = 0; m < 4; ++m) {
                if (s0 + m < B) {
                    float t0, t1, t2;
                    conv3_relu(X[m][0], X[m][1], X[m][2], w.x, w.y, w.z, w.w, t0, t1, t2);
                    cur[g]      += t0 + t1 + t2;
                    cur[16 + g]  = fmaf(t0, t0, fmaf(t1, t1, fmaf(t2, t2, cur[16 + g])));
                }
            }
        }
    }

    // xor-tree: 32 slots across 64 lanes -> lane (L&31) holds total of slot (L&31)
    int lane = t & 63, wid = t >> 6;
#pragma unroll
    for (int i = 0; i < 32; ++i) cur[i] += __shfl_xor(cur[i], 32, 64);
#pragma unroll
    for (int half = 16; half >= 1; half >>= 1) {
#pragma unroll
        for (int i = 0; i < half; ++i) {
            bool up = (lane & half);
            float keep = up ? cur[i + half] : cur[i];
            float send = up ? cur[i] : cur[i + half];
            cur[i] = keep + __shfl_xor(send, half, 64);
        }
    }
    __shared__ float red[4][32];
    if (lane < 32) red[wid][lane] = cur[0];
    __syncthreads();
    if (t < 32)
        partials[blockIdx.x * 32 + t] = red[0][t] + red[1][t] + red[2][t] + red[3][t];
}

// ---------------------------------------------------------------------------
// Finalize 1: BN1 scale/shift, fold into conv2 weights (padding-aware bias).
// ---------------------------------------------------------------------------
__global__ __launch_bounds__(256) void k_fin1(const float* __restrict__ partials,
                                              const float* __restrict__ g1,
                                              const float* __restrict__ bt1,
                                              const float* __restrict__ w2,
                                              const float* __restrict__ b2,
                                              float* __restrict__ w2f,
                                              float* __restrict__ b2f,
                                              float Ninv, int nb)
{
    __shared__ float4 red4[32][8];
    __shared__ float tot[32];
    __shared__ float ssc[16], ssh[16];
    int t = threadIdx.x;
    {
        int v4 = t & 7, c = t >> 3;  // 8 float4 slots cover 32 floats; 32 chunks
        float4 a = make_float4(0.f, 0.f, 0.f, 0.f);
        for (int b = c; b < nb; b += 32) {
            float4 p = ((const float4*)partials)[b * 8 + v4];
            a.x += p.x; a.y += p.y; a.z += p.z; a.w += p.w;
        }
        red4[c][v4] = a;
    }
    __syncthreads();
    if (t < 8) {
        float4 a = make_float4(0.f, 0.f, 0.f, 0.f);
#pragma unroll
        for (int c = 0; c < 32; ++c) {
            float4 p = red4[c][t];
            a.x += p.x; a.y += p.y; a.z += p.z; a.w += p.w;
        }
        tot[4*t+0] = a.x; tot[4*t+1] = a.y; tot[4*t+2] = a.z; tot[4*t+3] = a.w;
    }
    __syncthreads();
    if (t < 16) {
        float mean = tot[t] * Ninv;
        float var  = fmaxf(tot[16 + t] * Ninv - mean * mean, 0.f);
        float rstd = rsqrtf(var + EPSV);
        float sc = g1[t] * rstd;
        ssc[t] = sc;
        ssh[t] = bt1[t] - mean * sc;
    }
    __syncthreads();
    if (t < 96) {
        int o = t / 3, p = t % 3;
        int g = o >> 1;
        w2f[t] = w2[t] * ssc[g];
        float wv0 = w2[3*o], wv1 = w2[3*o+1], wv2 = w2[3*o+2];
        float sv = (p == 0) ? (wv1 + wv2) : ((p == 1) ? (wv0 + wv1 + wv2) : (wv0 + wv1));
        b2f[t] = b2[o] + ssh[g] * sv;
    }
}

// ---------------------------------------------------------------------------
// Pass 2: per-channel sum/sumsq of relu(conv2(bn1(relu1))), 32 channels.
// One lane = 4 consecutive samples; all weights LDS-broadcast; no per-sample
// cross-lane ops. Tail: xor-tree over 64 slots.
// partials[block*64 + v]: v<32 sum[ch v], v>=32 sq[ch v-32]
// ---------------------------------------------------------------------------
__global__ __launch_bounds__(256) void k_stats2(const float* __restrict__ x,
                                                const float* __restrict__ w1,
                                                const float* __restrict__ b1,
                                                const float* __restrict__ w2f,
                                                const float* __restrict__ b2f,
                                                float* __restrict__ partials,
                                                int B)
{
    __shared__ float4 sW1[16];
    __shared__ float4 sU[32];   // ua,ub,uc,c0
    __shared__ float2 sC[32];   // c1,c2
    int t = threadIdx.x;
    if (t < 16) sW1[t] = make_float4(w1[3*t], w1[3*t+1], w1[3*t+2], b1[t]);
    else if (t >= 32 && t < 64) {
        int o = t - 32;
        sU[o] = make_float4(w2f[3*o], w2f[3*o+1], w2f[3*o+2], b2f[3*o]);
        sC[o] = make_float2(b2f[3*o+1], b2f[3*o+2]);
    }
    __syncthreads();

    float cur[64];  // [0,32): sum, [32,64): sq
#pragma unroll
    for (int i = 0; i < 64; ++i) cur[i] = 0.f;

    int nchunk = (B + 3) >> 2;
    for (int ch = blockIdx.x * 256 + t; ch < nchunk; ch += gridDim.x * 256) {
        int s0 = ch << 2;
        float X[4][3];
        if (s0 + 4 <= B) {
            const float4* xp = (const float4*)(x + (size_t)s0 * 3);
            float4 A = xp[0], Bq = xp[1], Cq = xp[2];
            X[0][0]=A.x;  X[0][1]=A.y;  X[0][2]=A.z;
            X[1][0]=A.w;  X[1][1]=Bq.x; X[1][2]=Bq.y;
            X[2][0]=Bq.z; X[2][1]=Bq.w; X[2][2]=Cq.x;
            X[3][0]=Cq.y; X[3][1]=Cq.z; X[3][2]=Cq.w;
        } else {
#pragma unroll
            for (int m = 0; m < 4; ++m) {
                int s = s0 + m;
                if (s < B) { X[m][0]=x[3*s]; X[m][1]=x[3*s+1]; X[m][2]=x[3*s+2]; }
                else { X[m][0]=X[m][1]=X[m][2]=0.f; }
            }
        }
#pragma unroll
        for (int g = 0; g < 16; ++g) {
            float4 w = sW1[g];
            float r[4][3];
#pragma unroll
            for (int m = 0; m < 4; ++m)
                conv3_relu(X[m][0], X[m][1], X[m][2], w.x, w.y, w.z, w.w,
                           r[m][0], r[m][1], r[m][2]);
#pragma unroll
            for (int jj = 0; jj < 2; ++jj) {
                int o = 2 * g + jj;
                float4 u = sU[o];
                float2 cc = sC[o];
#pragma unroll
                for (int m = 0; m < 4; ++m) {
                    if (s0 + m < B) {
                        float v0 = fmaxf(fmaf(u.y, r[m][0], fmaf(u.z, r[m][1], u.w)), 0.f);
                        float v1 = fmaxf(fmaf(u.x, r[m][0], fmaf(u.y, r[m][1], fmaf(u.z, r[m][2], cc.x))), 0.f);
                        float v2 = fmaxf(fmaf(u.x, r[m][1], fmaf(u.y, r[m][2], cc.y)), 0.f);
                        cur[o]      += v0 + v1 + v2;
                        cur[32 + o]  = fmaf(v0, v0, fmaf(v1, v1, fmaf(v2, v2, cur[32 + o])));
                    }
                }
            }
        }
    }

    // xor-tree: 64 slots across 64 lanes -> lane L holds total of slot L
    int lane = t & 63, wid = t >> 6;
#pragma unroll
    for (int half = 32; half >= 1; half >>= 1) {
#pragma unroll
        for (int i = 0; i < half; ++i) {
            bool up = (lane & half);
            float keep = up ? cur[i + half] : cur[i];
            float send = up ? cur[i] : cur[i + half];
            cur[i] = keep + __shfl_xor(send, half, 64);
        }
    }
    __shared__ float red[4][64];
    red[wid][lane] = cur[0];
    __syncthreads();
    if (t < 64)
        partials[blockIdx.x * 64 + t] = red[0][t] + red[1][t] + red[2][t] + red[3][t];
}

// ---------------------------------------------------------------------------
// Finalize 2: BN2 scale/shift, fold BN2 + mean(1/3) into fc1.
// ---------------------------------------------------------------------------
__global__ __launch_bounds__(256) void k_fin2(const float* __restrict__ partials,
                                              const float* __restrict__ g2,
                                              const float* __restrict__ bt2,
                                              const float* __restrict__ fw1,
                                              const float* __restrict__ fb1,
                                              float* __restrict__ fw1s,
                                              float* __restrict__ c1,
                                              float Ninv, int nb)
{
    __shared__ float4 red4[16][16];
    __shared__ float tot[64];
    __shared__ float ssc[32], ssh[32];
    int t = threadIdx.x;
    {
        int v4 = t & 15, c = t >> 4;  // 16 float4 slots cover 64 floats; 16 chunks
        float4 a = make_float4(0.f, 0.f, 0.f, 0.f);
        for (int b = c; b < nb; b += 16) {
            float4 p = ((const float4*)partials)[b * 16 + v4];
            a.x += p.x; a.y += p.y; a.z += p.z; a.w += p.w;
        }
        red4[c][v4] = a;
    }
    __syncthreads();
    if (t < 16) {
        float4 a = make_float4(0.f, 0.f, 0.f, 0.f);
#pragma unroll
        for (int c = 0; c < 16; ++c) {
            float4 p = red4[c][t];
            a.x += p.x; a.y += p.y; a.z += p.z; a.w += p.w;
        }
        tot[4*t+0] = a.x; tot[4*t+1] = a.y; tot[4*t+2] = a.z; tot[4*t+3] = a.w;
    }
    __syncthreads();
    if (t < 32) {
        float mean = tot[t] * Ninv;
        float var  = fmaxf(tot[32 + t] * Ninv - mean * mean, 0.f);
        float rstd = rsqrtf(var + EPSV);
        float sc = g2[t] * rstd;
        ssc[t] = sc;
        ssh[t] = bt2[t] - mean * sc;
    }
    __syncthreads();
    for (int idx = t; idx < 512; idx += 256) {
        int c = idx & 31;
        fw1s[idx] = fw1[idx] * ssc[c] * (1.0f / 3.0f);
    }
    if (t < 16) {
        float a = fb1[t];
#pragma unroll
        for (int c = 0; c < 32; ++c) a = fmaf(fw1[t * 32 + c], ssh[c], a);
        c1[t] = a;
    }
}

// ---------------------------------------------------------------------------
// Pass 3: full forward, one lane = 2 consecutive samples, no cross-lane ops.
// All weights LDS-broadcast. fc1 j-outer with 2x2 partial accumulators.
// ---------------------------------------------------------------------------
__global__ __launch_bounds__(256) void k_final(const float* __restrict__ x,
                                               const float* __restrict__ w1,
                                               const float* __restrict__ b1,
                                               const float* __restrict__ w2f,
                                               const float* __restrict__ b2f,
                                               const float* __restrict__ fw1s,
                                               const float* __restrict__ c1,
                                               const float* __restrict__ fw2,
                                               const float* __restrict__ fb2,
                                               float* __restrict__ out,
                                               int B)
{
    __shared__ float4 sW1[16];
    __shared__ float4 sU[32];
    __shared__ float2 sC[32];
    __shared__ float4 sF[128];   // fw1s rows: sF[j*8+k] = fw1s[j*32+4k .. +3]
    __shared__ float2 sJ[16];    // (c1[j], fw2[j])
    __shared__ float  sb2;
    int t = threadIdx.x;
    if (t < 16) sW1[t] = make_float4(w1[3*t], w1[3*t+1], w1[3*t+2], b1[t]);
    else if (t >= 32 && t < 64) {
        int o = t - 32;
        sU[o] = make_float4(w2f[3*o], w2f[3*o+1], w2f[3*o+2], b2f[3*o]);
        sC[o] = make_float2(b2f[3*o+1], b2f[3*o+2]);
    } else if (t >= 64 && t < 192) {
        sF[t - 64] = ((const float4*)fw1s)[t - 64];
    } else if (t >= 192 && t < 208) {
        sJ[t - 192] = make_float2(c1[t - 192], fw2[t - 192]);
    } else if (t == 224) {
        sb2 = fb2[0];
    }
    __syncthreads();

    int nchunk = (B + 1) >> 1;
    for (int ch = blockIdx.x * 256 + t; ch < nchunk; ch += gridDim.x * 256) {
        int s0 = ch << 1;
        bool pair = (s0 + 2 <= B);
        float xA0, xA1, xA2, xB0, xB1, xB2;
        if (pair) {
            const float2* xp = (const float2*)(x + (size_t)s0 * 3);
            float2 a = xp[0], b = xp[1], c = xp[2];
            xA0 = a.x; xA1 = a.y; xA2 = b.x;
            xB0 = b.y; xB1 = c.x; xB2 = c.y;
        } else {
            xA0 = x[3*s0]; xA1 = x[3*s0+1]; xA2 = x[3*s0+2];
            xB0 = xB1 = xB2 = 0.f;
        }

        float sA[32], sB[32];
#pragma unroll
        for (int g = 0; g < 16; ++g) {
            float4 w = sW1[g];
            float rA0, rA1, rA2, rB0, rB1, rB2;
            conv3_relu(xA0, xA1, xA2, w.x, w.y, w.z, w.w, rA0, rA1, rA2);
            conv3_relu(xB0, xB1, xB2, w.x, w.y, w.z, w.w, rB0, rB1, rB2);
#pragma unroll
            for (int jj = 0; jj < 2; ++jj) {
                int o = 2 * g + jj;
                float4 u = sU[o];
                float2 cc = sC[o];
                float a0 = fmaxf(fmaf(u.y, rA0, fmaf(u.z, rA1, u.w)), 0.f);
                float a1 = fmaxf(fmaf(u.x, rA0, fmaf(u.y, rA1, fmaf(u.z, rA2, cc.x))), 0.f);
                float a2 = fmaxf(fmaf(u.x, rA1, fmaf(u.y, rA2, cc.y)), 0.f);
                sA[o] = a0 + a1 + a2;
                float b0 = fmaxf(fmaf(u.y, rB0, fmaf(u.z, rB1, u.w)), 0.f);
                float b1v = fmaxf(fmaf(u.x, rB0, fmaf(u.y, rB1, fmaf(u.z, rB2, cc.x))), 0.f);
                float b2v = fmaxf(fmaf(u.x, rB1, fmaf(u.y, rB2, cc.y)), 0.f);
                sB[o] = b0 + b1v + b2v;
            }
        }

        float base = sb2;
        float outA = base, outB = base;
#pragma unroll
        for (int j = 0; j < 16; ++j) {
            float a0 = 0.f, a1 = 0.f, b0 = 0.f, b1v = 0.f;
#pragma unroll
            for (int k = 0; k < 8; ++k) {
                float4 f = sF[j * 8 + k];
                a0  = fmaf(f.x, sA[4*k+0], a0);
                a1  = fmaf(f.y, sA[4*k+1], a1);
                a0  = fmaf(f.z, sA[4*k+2], a0);
                a1  = fmaf(f.w, sA[4*k+3], a1);
                b0  = fmaf(f.x, sB[4*k+0], b0);
                b1v = fmaf(f.y, sB[4*k+1], b1v);
                b0  = fmaf(f.z, sB[4*k+2], b0);
                b1v = fmaf(f.w, sB[4*k+3], b1v);
            }
            float2 jw = sJ[j];
            float hA = fmaxf(a0 + a1 + jw.x, 0.f);
            float hB = fmaxf(b0 + b1v + jw.x, 0.f);
            outA = fmaf(jw.y, hA, outA);
            outB = fmaf(jw.y, hB, outB);
        }
        if (pair) {
            ((float2*)(out + s0))[0] = make_float2(outA, outB);
        } else {
            out[s0] = outA;
        }
    }
}

// ---------------------------------------------------------------------------
extern "C" void kernel_launch(void* const* d_in, const int* in_sizes, int n_in,
                              void* d_out, int out_size, void* d_ws, size_t ws_size,
                              hipStream_t stream)
{
    const float* x   = (const float*)d_in[0];
    const float* w1  = (const float*)d_in[1];
    const float* b1  = (const float*)d_in[2];
    const float* g1  = (const float*)d_in[3];
    const float* bt1 = (const float*)d_in[4];
    const float* w2  = (const float*)d_in[5];
    const float* b2  = (const float*)d_in[6];
    const float* g2  = (const float*)d_in[7];
    const float* bt2 = (const float*)d_in[8];
    const float* fw1 = (const float*)d_in[9];
    const float* fb1 = (const float*)d_in[10];
    const float* fw2 = (const float*)d_in[11];
    const float* fb2 = (const float*)d_in[12];

    int B = in_sizes[0] / 3;

    // stats grids: one lane per 4-sample chunk; exact fit for B=2^20
    int nb1 = 1024, nb2 = 1024;
    while ((size_t)(nb1 * 32 + nb2 * 64 + 720) * sizeof(float) > ws_size && nb1 > 1) {
        nb1 >>= 1; nb2 >>= 1;
    }
    {   // don't launch more stats blocks than there are chunks
        int need = ((B + 3) / 4 + 255) / 256;
        if (nb1 > need && need > 0) nb1 = need;
        if (nb2 > need && need > 0) nb2 = need;
    }

    float* ws   = (float*)d_ws;
    float* p1   = ws;                               // nb1*32
    float* p2   = ws + (size_t)nb1 * 32;            // nb2*64
    float* w2f  = p2 + (size_t)nb2 * 64;            // 96
    float* b2f  = w2f + 96;                         // 96
    float* fw1s = b2f + 96;                         // 512
    float* c1   = fw1s + 512;                       // 16

    float Ninv = 1.0f / (3.0f * (float)B);

    int gridF = ((B + 1) / 2 + 255) / 256;          // 2048 for B=2^20

    k_stats1<<<nb1, 256, 0, stream>>>(x, w1, b1, p1, B);
    k_fin1<<<1, 256, 0, stream>>>(p1, g1, bt1, w2, b2, w2f, b2f, Ninv, nb1);
    k_stats2<<<nb2, 256, 0, stream>>>(x, w1, b1, w2f, b2f, p2, B);
    k_fin2<<<1, 256, 0, stream>>>(p2, g2, bt2, fw1, fb1, fw1s, c1, Ninv, nb2);
    k_final<<<gridF, 256, 0, stream>>>(x, w1, b1, w2f, b2f, fw1s, c1,
                                       fw2, fb2, (float*)d_out, B);
}

// Round 5
// 174.988 us; speedup vs baseline: 6.5442x; 3.5791x over previous
//
#include <hip/hip_runtime.h>
#include <math.h>

#define EPSV 1e-5f

// conv1 (3-tap, zero-pad) + relu at the 3 positions of one sample
__device__ __forceinline__ void conv3_relu(float x0, float x1, float x2,
                                           float wa, float wb, float wc, float bb,
                                           float& t0, float& t1, float& t2)
{
    t0 = fmaxf(fmaf(wb, x0, fmaf(wc, x1, bb)), 0.f);
    t1 = fmaxf(fmaf(wa, x0, fmaf(wb, x1, fmaf(wc, x2, bb))), 0.f);
    t2 = fmaxf(fmaf(wa, x1, fmaf(wb, x2, bb)), 0.f);
}

// ---------------------------------------------------------------------------
// Pass 1 (R2-proven body): per-channel sum/sumsq of relu(conv1(x)+b1).
// Weights lane-uniform (SGPRs). 4 samples/iter via float4 loads.
// partials[block*32 + v]: v<16 sum, v>=16 sq
// ---------------------------------------------------------------------------
__global__ __launch_bounds__(256) void k_stats1(const float* __restrict__ x,
                                                const float* __restrict__ w1,
                                                const float* __restrict__ b1,
                                                float* __restrict__ partials,
                                                int B)
{
    float W[16][3], Bv[16];
#pragma unroll
    for (int o = 0; o < 16; ++o) {
        W[o][0] = w1[3*o]; W[o][1] = w1[3*o+1]; W[o][2] = w1[3*o+2];
        Bv[o] = b1[o];
    }
    float sum[16], sq[16];
#pragma unroll
    for (int i = 0; i < 16; ++i) { sum[i] = 0.f; sq[i] = 0.f; }

    auto acc1 = [&](float x0, float x1, float x2) {
#pragma unroll
        for (int o = 0; o < 16; ++o) {
            float t0, t1, t2;
            conv3_relu(x0, x1, x2, W[o][0], W[o][1], W[o][2], Bv[o], t0, t1, t2);
            sum[o] += t0 + t1 + t2;
            sq[o] = fmaf(t0, t0, fmaf(t1, t1, fmaf(t2, t2, sq[o])));
        }
    };

    long long t = (long long)blockIdx.x * 256 + threadIdx.x;
    long long nth = (long long)gridDim.x * 256;
    long long nquad = ((long long)B + 3) >> 2;
    for (long long qd = t; qd < nquad; qd += nth) {
        long long s0 = qd << 2;
        if (s0 + 4 <= (long long)B) {
            const float4* xp = (const float4*)(x + s0 * 3);
            float4 A = xp[0], Bq = xp[1], Cq = xp[2];
            acc1(A.x, A.y, A.z);
            acc1(A.w, Bq.x, Bq.y);
            acc1(Bq.z, Bq.w, Cq.x);
            acc1(Cq.y, Cq.z, Cq.w);
        } else {
            for (int k = 0; k < 4; ++k)
                if (s0 + k < (long long)B)
                    acc1(x[3*(s0+k)], x[3*(s0+k)+1], x[3*(s0+k)+2]);
        }
    }

    __shared__ float red[4][32];
    int lane = threadIdx.x & 63, wid = threadIdx.x >> 6;
#pragma unroll
    for (int v = 0; v < 16; ++v) {
        float a = sum[v], b = sq[v];
#pragma unroll
        for (int off = 32; off >= 1; off >>= 1) {
            a += __shfl_down(a, off, 64);
            b += __shfl_down(b, off, 64);
        }
        if (lane == 0) { red[wid][v] = a; red[wid][16 + v] = b; }
    }
    __syncthreads();
    if (threadIdx.x < 32) {
        partials[blockIdx.x * 32 + threadIdx.x] =
            red[0][threadIdx.x] + red[1][threadIdx.x] +
            red[2][threadIdx.x] + red[3][threadIdx.x];
    }
}

// ---------------------------------------------------------------------------
// Finalize 1: BN1 scale/shift, fold into conv2 weights (padding-aware bias).
// ---------------------------------------------------------------------------
__global__ __launch_bounds__(256) void k_fin1(const float* __restrict__ partials,
                                              const float* __restrict__ g1,
                                              const float* __restrict__ bt1,
                                              const float* __restrict__ w2,
                                              const float* __restrict__ b2,
                                              float* __restrict__ w2f,
                                              float* __restrict__ b2f,
                                              float Ninv, int nb)
{
    __shared__ float4 red4[32][8];
    __shared__ float tot[32];
    __shared__ float ssc[16], ssh[16];
    int t = threadIdx.x;
    {
        int v4 = t & 7, c = t >> 3;
        float4 a = make_float4(0.f, 0.f, 0.f, 0.f);
        for (int b = c; b < nb; b += 32) {
            float4 p = ((const float4*)partials)[b * 8 + v4];
            a.x += p.x; a.y += p.y; a.z += p.z; a.w += p.w;
        }
        red4[c][v4] = a;
    }
    __syncthreads();
    if (t < 8) {
        float4 a = make_float4(0.f, 0.f, 0.f, 0.f);
#pragma unroll
        for (int c = 0; c < 32; ++c) {
            float4 p = red4[c][t];
            a.x += p.x; a.y += p.y; a.z += p.z; a.w += p.w;
        }
        tot[4*t+0] = a.x; tot[4*t+1] = a.y; tot[4*t+2] = a.z; tot[4*t+3] = a.w;
    }
    __syncthreads();
    if (t < 16) {
        float mean = tot[t] * Ninv;
        float var  = fmaxf(tot[16 + t] * Ninv - mean * mean, 0.f);
        float rstd = rsqrtf(var + EPSV);
        float sc = g1[t] * rstd;
        ssc[t] = sc;
        ssh[t] = bt1[t] - mean * sc;
    }
    __syncthreads();
    if (t < 96) {
        int o = t / 3, p = t % 3;
        int g = o >> 1;
        w2f[t] = w2[t] * ssc[g];
        float wv0 = w2[3*o], wv1 = w2[3*o+1], wv2 = w2[3*o+2];
        float sv = (p == 0) ? (wv1 + wv2) : ((p == 1) ? (wv0 + wv1 + wv2) : (wv0 + wv1));
        b2f[t] = b2[o] + ssh[g] * sv;
    }
}

// ---------------------------------------------------------------------------
// Pass 2 (R2-proven body): 32-channel sum/sumsq. Lane-quad split: q=tid&3
// handles conv groups [4q,4q+4) -> channels [8q,8q+8). Weights in registers.
// partials[block*64 + v]: v<32 sum, v>=32 sq
// ---------------------------------------------------------------------------
__global__ __launch_bounds__(256) void k_stats2(const float* __restrict__ x,
                                                const float* __restrict__ w1,
                                                const float* __restrict__ b1,
                                                const float* __restrict__ w2f,
                                                const float* __restrict__ b2f,
                                                float* __restrict__ partials,
                                                int B)
{
    const int q = threadIdx.x & 3;
    const int g0 = 4 * q;
    float W[4][3], Bv[4], U[8][3], C[8][3];
#pragma unroll
    for (int g = 0; g < 4; ++g) {
        W[g][0] = w1[3*(g0+g)]; W[g][1] = w1[3*(g0+g)+1]; W[g][2] = w1[3*(g0+g)+2];
        Bv[g] = b1[g0+g];
    }
#pragma unroll
    for (int j = 0; j < 8; ++j) {
        int o = 8*q + j;
        U[j][0] = w2f[3*o]; U[j][1] = w2f[3*o+1]; U[j][2] = w2f[3*o+2];
        C[j][0] = b2f[3*o]; C[j][1] = b2f[3*o+1]; C[j][2] = b2f[3*o+2];
    }
    float sum[8], sq[8];
#pragma unroll
    for (int i = 0; i < 8; ++i) { sum[i] = 0.f; sq[i] = 0.f; }

    auto acc2 = [&](float x0, float x1, float x2) {
#pragma unroll
        for (int g = 0; g < 4; ++g) {
            float r0, r1, r2;
            conv3_relu(x0, x1, x2, W[g][0], W[g][1], W[g][2], Bv[g], r0, r1, r2);
#pragma unroll
            for (int jj = 0; jj < 2; ++jj) {
                int j = 2*g + jj;
                float v0 = fmaxf(fmaf(U[j][1], r0, fmaf(U[j][2], r1, C[j][0])), 0.f);
                float v1 = fmaxf(fmaf(U[j][0], r0, fmaf(U[j][1], r1, fmaf(U[j][2], r2, C[j][1]))), 0.f);
                float v2 = fmaxf(fmaf(U[j][0], r1, fmaf(U[j][1], r2, C[j][2])), 0.f);
                sum[j] += v0 + v1 + v2;
                sq[j] = fmaf(v0, v0, fmaf(v1, v1, fmaf(v2, v2, sq[j])));
            }
        }
    };

    long long tq = ((long long)blockIdx.x * 256 + threadIdx.x) >> 2;
    long long nthq = ((long long)gridDim.x * 256) >> 2;
    long long npair = ((long long)B + 1) >> 1;
    for (long long sp = tq; sp < npair; sp += nthq) {
        long long s0 = sp << 1;
        if (s0 + 2 <= (long long)B) {
            const float2* xp = (const float2*)(x + sp * 6);
            float2 a = xp[0], b = xp[1], c = xp[2];
            acc2(a.x, a.y, b.x);
            acc2(b.y, c.x, c.y);
        } else if (s0 < (long long)B) {
            acc2(x[3*s0], x[3*s0+1], x[3*s0+2]);
        }
    }

    __shared__ float red[4][64];
    int lane = threadIdx.x & 63, wid = threadIdx.x >> 6;
#pragma unroll
    for (int v = 0; v < 8; ++v) {
        float a = sum[v], b = sq[v];
#pragma unroll
        for (int off = 4; off <= 32; off <<= 1) {
            a += __shfl_down(a, off, 64);
            b += __shfl_down(b, off, 64);
        }
        if (lane < 4) { red[wid][8*lane + v] = a; red[wid][32 + 8*lane + v] = b; }
    }
    __syncthreads();
    if (threadIdx.x < 64) {
        partials[blockIdx.x * 64 + threadIdx.x] =
            red[0][threadIdx.x] + red[1][threadIdx.x] +
            red[2][threadIdx.x] + red[3][threadIdx.x];
    }
}

// ---------------------------------------------------------------------------
// Finalize 2: BN2 scale/shift; fold BN2 + mean(1/3) into fc1, TRANSPOSED:
// fw1sT[o*16 + j] = fw1[j*32+o] * ssc[o] / 3  (k_final reads per-channel rows)
// c1[j] = fb1[j] + sum_c fw1[j*32+c] * ssh[c]
// ---------------------------------------------------------------------------
__global__ __launch_bounds__(256) void k_fin2(const float* __restrict__ partials,
                                              const float* __restrict__ g2,
                                              const float* __restrict__ bt2,
                                              const float* __restrict__ fw1,
                                              const float* __restrict__ fb1,
                                              float* __restrict__ fw1sT,
                                              float* __restrict__ c1,
                                              float Ninv, int nb)
{
    __shared__ float4 red4[16][16];
    __shared__ float tot[64];
    __shared__ float ssc[32], ssh[32];
    int t = threadIdx.x;
    {
        int v4 = t & 15, c = t >> 4;
        float4 a = make_float4(0.f, 0.f, 0.f, 0.f);
        for (int b = c; b < nb; b += 16) {
            float4 p = ((const float4*)partials)[b * 16 + v4];
            a.x += p.x; a.y += p.y; a.z += p.z; a.w += p.w;
        }
        red4[c][v4] = a;
    }
    __syncthreads();
    if (t < 16) {
        float4 a = make_float4(0.f, 0.f, 0.f, 0.f);
#pragma unroll
        for (int c = 0; c < 16; ++c) {
            float4 p = red4[c][t];
            a.x += p.x; a.y += p.y; a.z += p.z; a.w += p.w;
        }
        tot[4*t+0] = a.x; tot[4*t+1] = a.y; tot[4*t+2] = a.z; tot[4*t+3] = a.w;
    }
    __syncthreads();
    if (t < 32) {
        float mean = tot[t] * Ninv;
        float var  = fmaxf(tot[32 + t] * Ninv - mean * mean, 0.f);
        float rstd = rsqrtf(var + EPSV);
        float sc = g2[t] * rstd;
        ssc[t] = sc;
        ssh[t] = bt2[t] - mean * sc;
    }
    __syncthreads();
    for (int idx = t; idx < 512; idx += 256) {
        int o = idx >> 4, j = idx & 15;
        fw1sT[idx] = fw1[j * 32 + o] * ssc[o] * (1.0f / 3.0f);
    }
    if (t < 16) {
        float a = fb1[t];
#pragma unroll
        for (int c = 0; c < 32; ++c) a = fmaf(fw1[t * 32 + c], ssh[c], a);
        c1[t] = a;
    }
}

// ---------------------------------------------------------------------------
// Pass 3: full forward, one sample per lane, fc1 FUSED into the conv loop:
// per channel o, acc[j] += fw1sT[o][j] * s_o. Persistent state = acc[16]+x —
// tiny, so no spill (R4 lesson: big live arrays + full unroll spilled).
// #pragma unroll 4 bounds the scheduling window for the 128 LDS broadcasts.
// ---------------------------------------------------------------------------
__global__ __launch_bounds__(256) void k_final(const float* __restrict__ x,
                                               const float* __restrict__ w1,
                                               const float* __restrict__ b1,
                                               const float* __restrict__ w2f,
                                               const float* __restrict__ b2f,
                                               const float* __restrict__ fw1sT,
                                               const float* __restrict__ c1,
                                               const float* __restrict__ fw2,
                                               const float* __restrict__ fb2,
                                               float* __restrict__ out,
                                               int B)
{
    __shared__ float4 sW1[16];   // conv1 w + b
    __shared__ float4 sU[32];    // conv2 w + bias(pos0)
    __shared__ float2 sC[32];    // bias(pos1), bias(pos2)
    __shared__ float4 sFT[128];  // sFT[o*4+k] = fw1sT[o*16+4k .. +3]
    __shared__ float2 sJ[16];    // (c1[j], fw2[j])
    __shared__ float  sb2;
    int t = threadIdx.x;
    if (t < 16) sW1[t] = make_float4(w1[3*t], w1[3*t+1], w1[3*t+2], b1[t]);
    else if (t >= 32 && t < 64) {
        int o = t - 32;
        sU[o] = make_float4(w2f[3*o], w2f[3*o+1], w2f[3*o+2], b2f[3*o]);
        sC[o] = make_float2(b2f[3*o+1], b2f[3*o+2]);
    } else if (t >= 64 && t < 192) {
        sFT[t - 64] = ((const float4*)fw1sT)[t - 64];
    } else if (t >= 192 && t < 208) {
        sJ[t - 192] = make_float2(c1[t - 192], fw2[t - 192]);
    } else if (t == 224) {
        sb2 = fb2[0];
    }
    __syncthreads();

    for (int s = blockIdx.x * 256 + t; s < B; s += gridDim.x * 256) {
        float x0 = x[3*s], x1 = x[3*s+1], x2 = x[3*s+2];

        float acc[16];
#pragma unroll
        for (int j = 0; j < 16; ++j) acc[j] = 0.f;

#pragma unroll 4
        for (int g = 0; g < 16; ++g) {
            float4 w = sW1[g];
            float r0, r1, r2;
            conv3_relu(x0, x1, x2, w.x, w.y, w.z, w.w, r0, r1, r2);
#pragma unroll
            for (int jj = 0; jj < 2; ++jj) {
                int o = 2 * g + jj;
                float4 u = sU[o];
                float2 cc = sC[o];
                float v0 = fmaxf(fmaf(u.y, r0, fmaf(u.z, r1, u.w)), 0.f);
                float v1 = fmaxf(fmaf(u.x, r0, fmaf(u.y, r1, fmaf(u.z, r2, cc.x))), 0.f);
                float v2 = fmaxf(fmaf(u.x, r1, fmaf(u.y, r2, cc.y)), 0.f);
                float so = v0 + v1 + v2;
#pragma unroll
                for (int k = 0; k < 4; ++k) {
                    float4 f = sFT[o * 4 + k];
                    acc[4*k+0] = fmaf(f.x, so, acc[4*k+0]);
                    acc[4*k+1] = fmaf(f.y, so, acc[4*k+1]);
                    acc[4*k+2] = fmaf(f.z, so, acc[4*k+2]);
                    acc[4*k+3] = fmaf(f.w, so, acc[4*k+3]);
                }
            }
        }

        float r = sb2;
#pragma unroll
        for (int j = 0; j < 16; ++j) {
            float2 jw = sJ[j];
            r = fmaf(jw.y, fmaxf(acc[j] + jw.x, 0.f), r);
        }
        out[s] = r;
    }
}

// ---------------------------------------------------------------------------
extern "C" void kernel_launch(void* const* d_in, const int* in_sizes, int n_in,
                              void* d_out, int out_size, void* d_ws, size_t ws_size,
                              hipStream_t stream)
{
    const float* x   = (const float*)d_in[0];
    const float* w1  = (const float*)d_in[1];
    const float* b1  = (const float*)d_in[2];
    const float* g1  = (const float*)d_in[3];
    const float* bt1 = (const float*)d_in[4];
    const float* w2  = (const float*)d_in[5];
    const float* b2  = (const float*)d_in[6];
    const float* g2  = (const float*)d_in[7];
    const float* bt2 = (const float*)d_in[8];
    const float* fw1 = (const float*)d_in[9];
    const float* fb1 = (const float*)d_in[10];
    const float* fw2 = (const float*)d_in[11];
    const float* fb2 = (const float*)d_in[12];

    int B = in_sizes[0] / 3;

    int nb1 = 1024, nb2 = 1024;
    while ((size_t)(nb1 * 32 + nb2 * 64 + 720) * sizeof(float) > ws_size && nb1 > 1) {
        nb1 >>= 1; nb2 >>= 1;
    }
    {
        int need = ((B + 3) / 4 + 255) / 256;
        if (nb1 > need && need > 0) nb1 = need;
        if (nb2 > need && need > 0) nb2 = need;
    }

    float* ws    = (float*)d_ws;
    float* p1    = ws;                               // nb1*32
    float* p2    = ws + (size_t)nb1 * 32;            // nb2*64
    float* w2f   = p2 + (size_t)nb2 * 64;            // 96
    float* b2f   = w2f + 96;                         // 96
    float* fw1sT = b2f + 96;                         // 512
    float* c1    = fw1sT + 512;                      // 16

    float Ninv = 1.0f / (3.0f * (float)B);

    int gridF = (B + 255) / 256;                     // 4096 for B=2^20
    if (gridF > 4096) gridF = 4096;

    k_stats1<<<nb1, 256, 0, stream>>>(x, w1, b1, p1, B);
    k_fin1<<<1, 256, 0, stream>>>(p1, g1, bt1, w2, b2, w2f, b2f, Ninv, nb1);
    k_stats2<<<nb2, 256, 0, stream>>>(x, w1, b1, w2f, b2f, p2, B);
    k_fin2<<<1, 256, 0, stream>>>(p2, g2, bt2, fw1, fb1, fw1sT, c1, Ninv, nb2);
    k_final<<<gridF, 256, 0, stream>>>(x, w1, b1, w2f, b2f, fw1sT, c1,
                                       fw2, fb2, (float*)d_out, B);
}